// Round 1
// baseline (226.069 us; speedup 1.0000x reference)
//
#include <hip/hip_runtime.h>
#include <math.h>

#define VOC      512
#define EMB      128
#define L_SEQ    32
#define NWORDS   16384
#define NCOLS    320   // sum_k 16*k for k=2..6
#define WPB      4     // words per block in conv kernel

// -------- Kernel 1: PE[c][col] = sum_i emb[c][i] * w_k[o][i][j] --------
// col layout: k=2 -> cols [0,32), k=3 -> [32,80), k=4 -> [80,144),
//             k=5 -> [144,224), k=6 -> [224,320); within a k-segment,
//             col = off_k + j*16 + o.
__global__ __launch_bounds__(256) void build_pe(
    const float* __restrict__ emb,
    const float* __restrict__ w2, const float* __restrict__ w3,
    const float* __restrict__ w4, const float* __restrict__ w5,
    const float* __restrict__ w6,
    float* __restrict__ pe)
{
    int idx = blockIdx.x * 256 + threadIdx.x;   // [0, 512*320)
    if (idx >= VOC * NCOLS) return;
    int c   = idx / NCOLS;
    int col = idx - c * NCOLS;

    int k, off; const float* w;
    if (col < 32)       { k = 2; off = 0;   w = w2; }
    else if (col < 80)  { k = 3; off = 32;  w = w3; }
    else if (col < 144) { k = 4; off = 80;  w = w4; }
    else if (col < 224) { k = 5; off = 144; w = w5; }
    else                { k = 6; off = 224; w = w6; }

    int r = col - off;
    int j = r >> 4;      // tap index
    int o = r & 15;      // filter index

    const float* e  = emb + c * EMB;
    const float* wp = w + (o * EMB) * k + j;   // stride k between channels
    float s = 0.f;
    #pragma unroll 8
    for (int i = 0; i < EMB; ++i) s += e[i] * wp[i * k];
    pe[c * NCOLS + col] = s;
}

// -------- Kernel 2: gather PE rows per char, shifted sums + max-pool --------
// Block = 320 threads = 4 words x 80 outputs. Thread map: o = tid>>2,
// wi = tid&3  -> each 64-lane wave covers exactly one kernel size k
// (wave w handles o in [16w, 16w+16)), so trip counts are wave-uniform.
__global__ __launch_bounds__(320) void conv_max(
    const int*   __restrict__ word,
    const float* __restrict__ pe,
    const float* __restrict__ b2, const float* __restrict__ b3,
    const float* __restrict__ b4, const float* __restrict__ b5,
    const float* __restrict__ b6,
    float*       __restrict__ out)
{
    __shared__ int sc[WPB * L_SEQ];   // premultiplied row offsets (c*320), <0 = unk

    const int tid   = threadIdx.x;
    const int wbase = blockIdx.x * WPB;

    if (tid < WPB * L_SEQ) {
        int c = word[wbase * L_SEQ + tid];          // coalesced 128 ints
        sc[tid] = (c >= 0) ? c * NCOLS : -(1 << 20);
    }
    __syncthreads();

    const int o  = tid >> 2;     // 0..79
    const int wi = tid & 3;      // 0..3
    const int kidx = o >> 4;     // wave-uniform
    const int ol   = o & 15;

    int k, pad, off; const float* bp;
    switch (kidx) {                    // scalar (wave-uniform) branch
        case 0:  k = 2; pad = 0; off = 0;   bp = b2; break;
        case 1:  k = 3; pad = 0; off = 32;  bp = b3; break;
        case 2:  k = 4; pad = 1; off = 80;  bp = b4; break;
        case 3:  k = 5; pad = 2; off = 144; bp = b5; break;
        default: k = 6; pad = 3; off = 224; bp = b6; break;
    }
    const int lout = L_SEQ + 2 * pad - k + 1;
    const float bias = bp[ol];
    const int*  cw   = sc + wi * L_SEQ;
    const int   colb = off + ol;

    float m = -INFINITY;
    for (int t = 0; t < lout; ++t) {
        float s = bias;
        #pragma unroll
        for (int j = 0; j < 6; ++j) {          // bounded unroll; guarded by j<k
            if (j < k) {
                int tp = t - pad + j;
                if (tp >= 0 && tp < L_SEQ) {
                    int cb = cw[tp];
                    if (cb >= 0) s += pe[cb + colb + (j << 4)];
                }
            }
        }
        m = fmaxf(m, s);
    }
    out[(wbase + wi) * 80 + o] = m;
}

extern "C" void kernel_launch(void* const* d_in, const int* in_sizes, int n_in,
                              void* d_out, int out_size, void* d_ws, size_t ws_size,
                              hipStream_t stream)
{
    const int*   word = (const int*)  d_in[0];
    const float* emb  = (const float*)d_in[1];
    const float* w2   = (const float*)d_in[2];
    const float* b2   = (const float*)d_in[3];
    const float* w3   = (const float*)d_in[4];
    const float* b3   = (const float*)d_in[5];
    const float* w4   = (const float*)d_in[6];
    const float* b4   = (const float*)d_in[7];
    const float* w5   = (const float*)d_in[8];
    const float* b5   = (const float*)d_in[9];
    const float* w6   = (const float*)d_in[10];
    const float* b6   = (const float*)d_in[11];
    float* out = (float*)d_out;
    float* pe  = (float*)d_ws;        // 512*320*4 = 655360 bytes

    // Kernel 1: build PE table (512x320)
    build_pe<<<(VOC * NCOLS + 255) / 256, 256, 0, stream>>>(
        emb, w2, w3, w4, w5, w6, pe);

    // Kernel 2: gather + shifted sums + max-pool
    conv_max<<<NWORDS / WPB, 320, 0, stream>>>(
        word, pe, b2, b3, b4, b5, b6, out);
}

// Round 2
// 173.808 us; speedup vs baseline: 1.3007x; 1.3007x over previous
//
#include <hip/hip_runtime.h>
#include <math.h>

#define VOC      512
#define EMB      128
#define L_SEQ    32
#define NWORDS   16384
#define WPB      4      // words per block in conv kernel
#define ROWF     416    // floats per PE row: 16*(2+4+4+8+8)

// PE row layout (per char c): 5 k-segments, each [filter ol][tap j] with the
// tap dim padded to jpad so every lane's taps are one aligned vector load.
//   k=2: jpad=2, base 0    (32 floats)
//   k=3: jpad=4, base 32   (64)   taps j>=3 are zero-pad
//   k=4: jpad=4, base 96   (64)
//   k=5: jpad=8, base 160  (128)  j>=5 zero
//   k=6: jpad=8, base 288  (128)  j>=6 zero
// Row VOC (index 512) is all-zero: target for unk (<0) chars.

// -------- Kernel 1: build PE table, one block per char row --------
__global__ __launch_bounds__(416) void build_pe2(
    const float* __restrict__ emb,
    const float* __restrict__ w2, const float* __restrict__ w3,
    const float* __restrict__ w4, const float* __restrict__ w5,
    const float* __restrict__ w6,
    float* __restrict__ pe2)
{
    const int c   = blockIdx.x;          // 0..512 (512 = zero row)
    const int tid = threadIdx.x;         // 0..415
    float* row = pe2 + c * ROWF;

    if (c == VOC) { row[tid] = 0.f; return; }   // block-uniform

    __shared__ float e[EMB];
    if (tid < EMB) e[tid] = emb[c * EMB + tid];
    __syncthreads();

    int k, jpad, base; const float* w;
    if (tid < 32)       { k = 2; jpad = 2; base = 0;   w = w2; }
    else if (tid < 96)  { k = 3; jpad = 4; base = 32;  w = w3; }
    else if (tid < 160) { k = 4; jpad = 4; base = 96;  w = w4; }
    else if (tid < 288) { k = 5; jpad = 8; base = 160; w = w5; }
    else                { k = 6; jpad = 8; base = 288; w = w6; }

    const int r  = tid - base;
    const int ol = (jpad == 2) ? (r >> 1) : (jpad == 4) ? (r >> 2) : (r >> 3);
    const int j  = r & (jpad - 1);

    float s = 0.f;
    if (j < k) {
        const float* wp = w + (ol * EMB) * k + j;
        #pragma unroll 16
        for (int i = 0; i < EMB; ++i) s += e[i] * wp[i * k];
    }
    row[tid] = s;
}

// -------- Kernel 2: tp-major sliding-window conv + max --------
template<int K, int PAD, int SEGOFF, int JPAD>
__device__ __forceinline__ float convf(const float* __restrict__ pe2,
                                       const int* __restrict__ sc,
                                       int wi, int ol, float bias)
{
    constexpr int LOUT = L_SEQ + 2 * PAD - K + 1;
    float s[LOUT];
    #pragma unroll
    for (int t = 0; t < LOUT; ++t) s[t] = bias;

    const int lanebase = SEGOFF + ol * JPAD;

    #pragma unroll
    for (int tp = 0; tp < L_SEQ; ++tp) {
        const float* p = pe2 + sc[tp * WPB + wi] + lanebase;
        float v[K];
        if constexpr (K == 2) {
            float2 q = *(const float2*)p; v[0] = q.x; v[1] = q.y;
        } else if constexpr (K == 3) {
            float4 q = *(const float4*)p; v[0] = q.x; v[1] = q.y; v[2] = q.z;
        } else if constexpr (K == 4) {
            float4 q = *(const float4*)p;
            v[0] = q.x; v[1] = q.y; v[2] = q.z; v[3] = q.w;
        } else if constexpr (K == 5) {
            float4 q = *(const float4*)p;
            v[0] = q.x; v[1] = q.y; v[2] = q.z; v[3] = q.w; v[4] = p[4];
        } else {
            float4 q = *(const float4*)p;
            float2 r = *(const float2*)(p + 4);
            v[0] = q.x; v[1] = q.y; v[2] = q.z; v[3] = q.w; v[4] = r.x; v[5] = r.y;
        }
        #pragma unroll
        for (int j = 0; j < K; ++j) {
            constexpr int dummy = 0; (void)dummy;
            int t = tp + PAD - j;             // compile-time per (tp,j)
            if (t >= 0 && t < LOUT) s[t] += v[j];
        }
    }

    float m = s[0];
    #pragma unroll
    for (int t = 1; t < LOUT; ++t) m = fmaxf(m, s[t]);
    return m;
}

__global__ __launch_bounds__(320) void conv_max(
    const int*   __restrict__ word,
    const float* __restrict__ pe2,
    const float* __restrict__ b2, const float* __restrict__ b3,
    const float* __restrict__ b4, const float* __restrict__ b5,
    const float* __restrict__ b6,
    float*       __restrict__ out)
{
    // sc[tp][wi]: 4 consecutive banks per tp -> conflict-free broadcast
    __shared__ int sc[L_SEQ * WPB];

    const int tid   = threadIdx.x;
    const int wbase = blockIdx.x * WPB;

    if (tid < WPB * L_SEQ) {
        int c  = word[wbase * L_SEQ + tid];      // coalesced
        int w  = tid >> 5;                       // word within block
        int tp = tid & 31;                       // char position
        sc[tp * WPB + w] = (c >= 0 ? c : VOC) * ROWF;
    }
    __syncthreads();

    const int o    = tid >> 2;      // 0..79
    const int wi   = tid & 3;       // 0..3
    const int kidx = o >> 4;        // wave-uniform
    const int ol   = o & 15;

    float m;
    switch (kidx) {
        case 0:  m = convf<2, 0, 0,   2>(pe2, sc, wi, ol, b2[ol]); break;
        case 1:  m = convf<3, 0, 32,  4>(pe2, sc, wi, ol, b3[ol]); break;
        case 2:  m = convf<4, 1, 96,  4>(pe2, sc, wi, ol, b4[ol]); break;
        case 3:  m = convf<5, 2, 160, 8>(pe2, sc, wi, ol, b5[ol]); break;
        default: m = convf<6, 3, 288, 8>(pe2, sc, wi, ol, b6[ol]); break;
    }
    out[(wbase + wi) * 80 + o] = m;
}

extern "C" void kernel_launch(void* const* d_in, const int* in_sizes, int n_in,
                              void* d_out, int out_size, void* d_ws, size_t ws_size,
                              hipStream_t stream)
{
    const int*   word = (const int*)  d_in[0];
    const float* emb  = (const float*)d_in[1];
    const float* w2   = (const float*)d_in[2];
    const float* b2   = (const float*)d_in[3];
    const float* w3   = (const float*)d_in[4];
    const float* b3   = (const float*)d_in[5];
    const float* w4   = (const float*)d_in[6];
    const float* b4   = (const float*)d_in[7];
    const float* w5   = (const float*)d_in[8];
    const float* b5   = (const float*)d_in[9];
    const float* w6   = (const float*)d_in[10];
    const float* b6   = (const float*)d_in[11];
    float* out = (float*)d_out;
    float* pe2 = (float*)d_ws;        // (512+1)*416*4 = 853,632 bytes

    build_pe2<<<VOC + 1, 416, 0, stream>>>(emb, w2, w3, w4, w5, w6, pe2);

    conv_max<<<NWORDS / WPB, 320, 0, stream>>>(
        word, pe2, b2, b3, b4, b5, b6, out);
}

// Round 3
// 137.767 us; speedup vs baseline: 1.6410x; 1.2616x over previous
//
#include <hip/hip_runtime.h>
#include <hip/hip_fp16.h>
#include <math.h>

#define VOC      512
#define EMB      128
#define L_SEQ    32
#define NWORDS   16384
#define WPB      4      // words per block in conv kernel
#define ROWH     416    // halves per PE row: 16*(2+4+4+8+8)
#define CTILE    8      // chars per block in build kernel

// PE row layout (per char c), fp16: 5 k-segments, each [filter ol][tap j],
// tap dim padded to jpad so a lane's taps are ONE aligned 4/8/16B load.
//   k=2: jpad=2, half-base 0    k=3: jpad=4, base 32   k=4: jpad=4, base 96
//   k=5: jpad=8, base 160      k=6: jpad=8, base 288   (pad taps = 0)
// Row VOC (index 512) is all-zero: target for unk (<0) chars.

// -------- Kernel A: pack weights to Wt[i][col] (fp32), col = PE layout ----
__global__ __launch_bounds__(ROWH) void pack_wt(
    const float* __restrict__ w2, const float* __restrict__ w3,
    const float* __restrict__ w4, const float* __restrict__ w5,
    const float* __restrict__ w6,
    float* __restrict__ wt)
{
    const int i   = blockIdx.x;      // 0..127 input channel
    const int col = threadIdx.x;     // 0..415

    int k, jpad, base; const float* w;
    if (col < 32)       { k = 2; jpad = 2; base = 0;   w = w2; }
    else if (col < 96)  { k = 3; jpad = 4; base = 32;  w = w3; }
    else if (col < 160) { k = 4; jpad = 4; base = 96;  w = w4; }
    else if (col < 288) { k = 5; jpad = 8; base = 160; w = w5; }
    else                { k = 6; jpad = 8; base = 288; w = w6; }

    const int r  = col - base;
    const int ol = (jpad == 2) ? (r >> 1) : (jpad == 4) ? (r >> 2) : (r >> 3);
    const int j  = r & (jpad - 1);

    wt[i * ROWH + col] = (j < k) ? w[(ol * EMB + i) * k + j] : 0.f;
}

// -------- Kernel B: PE16[c][col] = sum_i emb[c][i] * Wt[i][col] ----------
__global__ __launch_bounds__(ROWH) void build_pe16(
    const float* __restrict__ emb,
    const float* __restrict__ wt,
    __half* __restrict__ pe)
{
    const int tid = threadIdx.x;     // 0..415 = col
    const int c0  = blockIdx.x * CTILE;

    if (c0 >= VOC) {                 // last block: the zero row (index 512)
        pe[VOC * ROWH + tid] = __float2half(0.f);
        return;
    }

    __shared__ float e[CTILE][EMB];  // 4 KB
    for (int idx = tid; idx < CTILE * EMB; idx += ROWH)
        e[idx >> 7][idx & 127] = emb[c0 * EMB + idx];
    __syncthreads();

    float s[CTILE];
    #pragma unroll
    for (int wc = 0; wc < CTILE; ++wc) s[wc] = 0.f;

    for (int i = 0; i < EMB; ++i) {
        float wv = wt[i * ROWH + tid];        // coalesced row stream (L2-hot)
        #pragma unroll
        for (int wc = 0; wc < CTILE; ++wc) s[wc] += e[wc][i] * wv;  // LDS bcast
    }

    #pragma unroll
    for (int wc = 0; wc < CTILE; ++wc)
        pe[(c0 + wc) * ROWH + tid] = __float2half(s[wc]);
}

// -------- Kernel C: tp-major sliding-window conv + max (fp16 PE) ---------
__device__ __forceinline__ float2 h2tof2(int u) {
    return __half22float2(__builtin_bit_cast(__half2, u));
}

template<int K, int PAD, int SEGH, int JPADH>
__device__ __forceinline__ float convf(const __half* __restrict__ pe,
                                       const int* __restrict__ sc,
                                       int wi, int ol, float bias)
{
    constexpr int LOUT = L_SEQ + 2 * PAD - K + 1;
    float s[LOUT];
    #pragma unroll
    for (int t = 0; t < LOUT; ++t) s[t] = bias;

    const int lanebase = SEGH + ol * JPADH;   // in halves

    #pragma unroll
    for (int tp = 0; tp < L_SEQ; ++tp) {
        const __half* p = pe + sc[tp * WPB + wi] + lanebase;
        float v[K];
        if constexpr (K == 2) {
            float2 f = h2tof2(*(const int*)p);
            v[0] = f.x; v[1] = f.y;
        } else if constexpr (K == 3) {
            int2 q = *(const int2*)p;
            float2 f0 = h2tof2(q.x), f1 = h2tof2(q.y);
            v[0] = f0.x; v[1] = f0.y; v[2] = f1.x;
        } else if constexpr (K == 4) {
            int2 q = *(const int2*)p;
            float2 f0 = h2tof2(q.x), f1 = h2tof2(q.y);
            v[0] = f0.x; v[1] = f0.y; v[2] = f1.x; v[3] = f1.y;
        } else if constexpr (K == 5) {
            int4 q = *(const int4*)p;
            float2 f0 = h2tof2(q.x), f1 = h2tof2(q.y), f2 = h2tof2(q.z);
            v[0] = f0.x; v[1] = f0.y; v[2] = f1.x; v[3] = f1.y; v[4] = f2.x;
        } else {
            int4 q = *(const int4*)p;
            float2 f0 = h2tof2(q.x), f1 = h2tof2(q.y), f2 = h2tof2(q.z);
            v[0] = f0.x; v[1] = f0.y; v[2] = f1.x; v[3] = f1.y;
            v[4] = f2.x; v[5] = f2.y;
        }
        #pragma unroll
        for (int j = 0; j < K; ++j) {
            int t = tp + PAD - j;             // compile-time per (tp,j)
            if (t >= 0 && t < LOUT) s[t] += v[j];
        }
    }

    float m = s[0];
    #pragma unroll
    for (int t = 1; t < LOUT; ++t) m = fmaxf(m, s[t]);
    return m;
}

__global__ __launch_bounds__(320) void conv_max(
    const int*   __restrict__ word,
    const __half* __restrict__ pe,
    const float* __restrict__ b2, const float* __restrict__ b3,
    const float* __restrict__ b4, const float* __restrict__ b5,
    const float* __restrict__ b6,
    float*       __restrict__ out)
{
    __shared__ int sc[L_SEQ * WPB];   // sc[tp][wi]: conflict-free

    const int tid   = threadIdx.x;
    const int wbase = blockIdx.x * WPB;

    if (tid < WPB * L_SEQ) {
        int c  = word[wbase * L_SEQ + tid];      // coalesced
        int w  = tid >> 5;
        int tp = tid & 31;
        sc[tp * WPB + w] = (c >= 0 ? c : VOC) * ROWH;
    }
    __syncthreads();

    const int o    = tid >> 2;      // 0..79
    const int wi   = tid & 3;       // 0..3
    const int kidx = o >> 4;        // wave-uniform
    const int ol   = o & 15;

    float m;
    switch (kidx) {
        case 0:  m = convf<2, 0, 0,   2>(pe, sc, wi, ol, b2[ol]); break;
        case 1:  m = convf<3, 0, 32,  4>(pe, sc, wi, ol, b3[ol]); break;
        case 2:  m = convf<4, 1, 96,  4>(pe, sc, wi, ol, b4[ol]); break;
        case 3:  m = convf<5, 2, 160, 8>(pe, sc, wi, ol, b5[ol]); break;
        default: m = convf<6, 3, 288, 8>(pe, sc, wi, ol, b6[ol]); break;
    }
    out[(wbase + wi) * 80 + o] = m;
}

extern "C" void kernel_launch(void* const* d_in, const int* in_sizes, int n_in,
                              void* d_out, int out_size, void* d_ws, size_t ws_size,
                              hipStream_t stream)
{
    const int*   word = (const int*)  d_in[0];
    const float* emb  = (const float*)d_in[1];
    const float* w2   = (const float*)d_in[2];
    const float* b2   = (const float*)d_in[3];
    const float* w3   = (const float*)d_in[4];
    const float* b3   = (const float*)d_in[5];
    const float* w4   = (const float*)d_in[6];
    const float* b4   = (const float*)d_in[7];
    const float* w5   = (const float*)d_in[8];
    const float* b5   = (const float*)d_in[9];
    const float* w6   = (const float*)d_in[10];
    const float* b6   = (const float*)d_in[11];
    float* out = (float*)d_out;

    // ws layout: pe16 [513*416 halves = 426,816 B], then Wt fp32 at +430,080
    __half* pe16 = (__half*)d_ws;
    float*  wt   = (float*)((char*)d_ws + 430080);   // 128*416*4 = 212,992 B

    pack_wt<<<EMB, ROWH, 0, stream>>>(w2, w3, w4, w5, w6, wt);

    build_pe16<<<VOC / CTILE + 1, ROWH, 0, stream>>>(emb, wt, pe16);

    conv_max<<<NWORDS / WPB, 320, 0, stream>>>(
        word, pe16, b2, b3, b4, b5, b6, out);
}

// Round 4
// 136.315 us; speedup vs baseline: 1.6584x; 1.0107x over previous
//
#include <hip/hip_runtime.h>
#include <hip/hip_fp16.h>
#include <math.h>

#define VOC      512
#define EMB      128
#define L_SEQ    32
#define NWORDS   16384
#define ROWH     416    // halves per PE row: 16*(2+4+4+8+8)
#define ROWB     832    // bytes per PE row
#define CTILE    8      // chars per block in build kernel
#define WPB      16     // words per conv block

// PE row layout (per char c), fp16: 5 k-segments, each [filter ol][tap j],
// tap dim padded to jpad so a lane's taps are ONE aligned 4/8/16B load.
//   k=2: jpad=2, half-base 0    k=3: jpad=4, base 32   k=4: jpad=4, base 96
//   k=5: jpad=8, base 160      k=6: jpad=8, base 288   (pad taps = 0)
// Row VOC (index 512) is all-zero: target for unk (<0) chars.

// -------- Kernel A: pack weights to Wt[i][col] (fp32), col = PE layout ----
__global__ __launch_bounds__(ROWH) void pack_wt(
    const float* __restrict__ w2, const float* __restrict__ w3,
    const float* __restrict__ w4, const float* __restrict__ w5,
    const float* __restrict__ w6,
    float* __restrict__ wt)
{
    const int i   = blockIdx.x;      // 0..127 input channel
    const int col = threadIdx.x;     // 0..415

    int k, jpad, base; const float* w;
    if (col < 32)       { k = 2; jpad = 2; base = 0;   w = w2; }
    else if (col < 96)  { k = 3; jpad = 4; base = 32;  w = w3; }
    else if (col < 160) { k = 4; jpad = 4; base = 96;  w = w4; }
    else if (col < 288) { k = 5; jpad = 8; base = 160; w = w5; }
    else                { k = 6; jpad = 8; base = 288; w = w6; }

    const int r  = col - base;
    const int ol = (jpad == 2) ? (r >> 1) : (jpad == 4) ? (r >> 2) : (r >> 3);
    const int j  = r & (jpad - 1);

    wt[i * ROWH + col] = (j < k) ? w[(ol * EMB + i) * k + j] : 0.f;
}

// -------- Kernel B: PE16[c][col] = sum_i emb[c][i] * Wt[i][col] ----------
__global__ __launch_bounds__(ROWH) void build_pe16(
    const float* __restrict__ emb,
    const float* __restrict__ wt,
    __half* __restrict__ pe)
{
    const int tid = threadIdx.x;     // 0..415 = col
    const int c0  = blockIdx.x * CTILE;

    if (c0 >= VOC) {                 // last block: the zero row (index 512)
        pe[VOC * ROWH + tid] = __float2half(0.f);
        return;
    }

    __shared__ float e[CTILE][EMB];  // 4 KB
    for (int idx = tid; idx < CTILE * EMB; idx += ROWH)
        e[idx >> 7][idx & 127] = emb[c0 * EMB + idx];
    __syncthreads();

    float s[CTILE];
    #pragma unroll
    for (int wc = 0; wc < CTILE; ++wc) s[wc] = 0.f;

    for (int i = 0; i < EMB; ++i) {
        float wv = wt[i * ROWH + tid];        // coalesced row stream (L2-hot)
        #pragma unroll
        for (int wc = 0; wc < CTILE; ++wc) s[wc] += e[wc][i] * wv;  // LDS bcast
    }

    #pragma unroll
    for (int wc = 0; wc < CTILE; ++wc)
        pe[(c0 + wc) * ROWH + tid] = __float2half(s[wc]);
}

// -------- Kernel C: one k-segment per block, batched-MLP gather conv -----
__device__ __forceinline__ float2 h2tof2(int u) {
    return __half22float2(__builtin_bit_cast(__half2, u));
}

template<int K> struct LdT;
template<> struct LdT<2> { using T = int;  };
template<> struct LdT<3> { using T = int2; };
template<> struct LdT<4> { using T = int2; };
template<> struct LdT<5> { using T = int4; };
template<> struct LdT<6> { using T = int4; };

template<int K>
__device__ __forceinline__ void unpack(typename LdT<K>::T q, float* v) {
    if constexpr (K == 2) {
        float2 f = h2tof2(q); v[0] = f.x; v[1] = f.y;
    } else if constexpr (K == 3) {
        float2 f0 = h2tof2(q.x), f1 = h2tof2(q.y);
        v[0] = f0.x; v[1] = f0.y; v[2] = f1.x;
    } else if constexpr (K == 4) {
        float2 f0 = h2tof2(q.x), f1 = h2tof2(q.y);
        v[0] = f0.x; v[1] = f0.y; v[2] = f1.x; v[3] = f1.y;
    } else if constexpr (K == 5) {
        float2 f0 = h2tof2(q.x), f1 = h2tof2(q.y), f2 = h2tof2(q.z);
        v[0] = f0.x; v[1] = f0.y; v[2] = f1.x; v[3] = f1.y; v[4] = f2.x;
    } else {
        float2 f0 = h2tof2(q.x), f1 = h2tof2(q.y), f2 = h2tof2(q.z);
        v[0] = f0.x; v[1] = f0.y; v[2] = f1.x; v[3] = f1.y;
        v[4] = f2.x; v[5] = f2.y;
    }
}

template<int K, int PAD, int SEGH, int JPADH>
__device__ __forceinline__ float convseg(const char* __restrict__ peb,
                                         const int* __restrict__ sc,
                                         int w16, int ol, float bias)
{
    using LT = typename LdT<K>::T;
    constexpr int LOUT = L_SEQ + 2 * PAD - K + 1;
    const int lb = (SEGH + ol * JPADH) * 2;   // byte offset within row

    float s[LOUT];
    #pragma unroll
    for (int t = 0; t < LOUT; ++t) s[t] = bias;

    #pragma unroll
    for (int g = 0; g < 4; ++g) {
        // batch: 8 LDS reads, 8 offset adds, 8 gathers in flight
        int off[8];
        #pragma unroll
        for (int u = 0; u < 8; ++u)
            off[u] = sc[(g * 8 + u) * WPB + w16] + lb;
        LT q[8];
        #pragma unroll
        for (int u = 0; u < 8; ++u)
            q[u] = *(const LT*)(peb + off[u]);
        #pragma unroll
        for (int u = 0; u < 8; ++u) {
            const int tp = g * 8 + u;         // compile-time
            float v[K];
            unpack<K>(q[u], v);
            #pragma unroll
            for (int j = 0; j < K; ++j) {
                int t = tp + PAD - j;         // compile-time per (tp,j)
                if (t >= 0 && t < LOUT) s[t] += v[j];
            }
        }
    }

    float m = s[0];
    #pragma unroll
    for (int t = 1; t < LOUT; ++t) m = fmaxf(m, s[t]);
    return m;
}

__global__ __launch_bounds__(256, 4) void conv_max(
    const int*   __restrict__ word,
    const __half* __restrict__ pe,
    const float* __restrict__ b2, const float* __restrict__ b3,
    const float* __restrict__ b4, const float* __restrict__ b5,
    const float* __restrict__ b6,
    float*       __restrict__ out)
{
    __shared__ int sc[L_SEQ * WPB];   // [tp][w16] byte offsets; 2 KB

    const int tid   = threadIdx.x;
    const int seg   = blockIdx.x >> 10;        // 0..4, block-uniform
    const int wb    = blockIdx.x & 1023;
    const int wbase = wb * WPB;

    #pragma unroll
    for (int r = 0; r < 2; ++r) {
        int i = tid + r * 256;                 // 0..511
        int c = word[wbase * L_SEQ + i];       // coalesced
        sc[(i & 31) * WPB + (i >> 5)] = (c >= 0 ? c : VOC) * ROWB;
    }
    __syncthreads();

    const int lane = tid & 63;
    const int ol   = lane >> 2;                         // 0..15
    const int w16  = ((tid >> 6) << 2) | (lane & 3);    // 0..15

    const char* peb = (const char*)pe;
    float m;
    switch (seg) {
        case 0:  m = convseg<2, 0, 0,   2>(peb, sc, w16, ol, b2[ol]); break;
        case 1:  m = convseg<3, 0, 32,  4>(peb, sc, w16, ol, b3[ol]); break;
        case 2:  m = convseg<4, 1, 96,  4>(peb, sc, w16, ol, b4[ol]); break;
        case 3:  m = convseg<5, 2, 160, 8>(peb, sc, w16, ol, b5[ol]); break;
        default: m = convseg<6, 3, 288, 8>(peb, sc, w16, ol, b6[ol]); break;
    }
    out[(wbase + w16) * 80 + seg * 16 + ol] = m;
}

extern "C" void kernel_launch(void* const* d_in, const int* in_sizes, int n_in,
                              void* d_out, int out_size, void* d_ws, size_t ws_size,
                              hipStream_t stream)
{
    const int*   word = (const int*)  d_in[0];
    const float* emb  = (const float*)d_in[1];
    const float* w2   = (const float*)d_in[2];
    const float* b2   = (const float*)d_in[3];
    const float* w3   = (const float*)d_in[4];
    const float* b3   = (const float*)d_in[5];
    const float* w4   = (const float*)d_in[6];
    const float* b4   = (const float*)d_in[7];
    const float* w5   = (const float*)d_in[8];
    const float* b5   = (const float*)d_in[9];
    const float* w6   = (const float*)d_in[10];
    const float* b6   = (const float*)d_in[11];
    float* out = (float*)d_out;

    // ws layout: pe16 [513*416 halves = 426,816 B], then Wt fp32 at +430,080
    __half* pe16 = (__half*)d_ws;
    float*  wt   = (float*)((char*)d_ws + 430080);   // 128*416*4 = 212,992 B

    pack_wt<<<EMB, ROWH, 0, stream>>>(w2, w3, w4, w5, w6, wt);

    build_pe16<<<VOC / CTILE + 1, ROWH, 0, stream>>>(emb, wt, pe16);

    conv_max<<<5 * (NWORDS / WPB), 256, 0, stream>>>(
        word, pe16, b2, b3, b4, b5, b6, out);
}

// Round 5
// 106.699 us; speedup vs baseline: 2.1188x; 1.2776x over previous
//
#include <hip/hip_runtime.h>
#include <hip/hip_fp16.h>
#include <math.h>

#define VOC      512
#define EMB      128
#define L_SEQ    32
#define NWORDS   16384
#define NCOL     416     // 16*(2+4+4+8+8) padded cols
#define WPB      128     // words per conv block
#define SCPITCH  129     // sc row pitch (ints) -> conflict-free transpose

// Seg-major PE subtables (halves), taps padded to jpad, zeros for j>=k.
//   seg0 k=2 w=32H  base 0        seg1 k=3 w=64H  base 16416
//   seg2 k=4 w=64H  base 49248    seg3 k=5 w=128H base 82080
//   seg4 k=6 w=128H base 147744   total 213408 halves = 426816 B
// Row index VOC (512) in each subtable is all-zero (unk chars).
__device__ __constant__ int SEGBASE_H[5] = {0, 16416, 49248, 82080, 147744};
__device__ __constant__ int SEGW_H[5]    = {32, 64, 64, 128, 128};

// -------- Kernel A: pack weights to Wt[i][col] (fp32) --------
__global__ __launch_bounds__(NCOL) void pack_wt(
    const float* __restrict__ w2, const float* __restrict__ w3,
    const float* __restrict__ w4, const float* __restrict__ w5,
    const float* __restrict__ w6,
    float* __restrict__ wt)
{
    const int i   = blockIdx.x;      // input channel
    const int col = threadIdx.x;     // 0..415

    int k, jpad, base; const float* w;
    if (col < 32)       { k = 2; jpad = 2; base = 0;   w = w2; }
    else if (col < 96)  { k = 3; jpad = 4; base = 32;  w = w3; }
    else if (col < 160) { k = 4; jpad = 4; base = 96;  w = w4; }
    else if (col < 288) { k = 5; jpad = 8; base = 160; w = w5; }
    else                { k = 6; jpad = 8; base = 288; w = w6; }

    const int r  = col - base;
    const int ol = (jpad == 2) ? (r >> 1) : (jpad == 4) ? (r >> 2) : (r >> 3);
    const int j  = r & (jpad - 1);

    wt[i * NCOL + col] = (j < k) ? w[(ol * EMB + i) * k + j] : 0.f;
}

// -------- Kernel B: one block per char; write seg-major fp16 subtables ---
__device__ __forceinline__ void col_map(int col, int& seg, int& local) {
    if (col < 32)       { seg = 0; local = col; }
    else if (col < 96)  { seg = 1; local = col - 32; }
    else if (col < 160) { seg = 2; local = col - 96; }
    else if (col < 288) { seg = 3; local = col - 160; }
    else                { seg = 4; local = col - 288; }
}

__global__ __launch_bounds__(512) void build_pe16(
    const float* __restrict__ emb,
    const float* __restrict__ wt,
    __half* __restrict__ pe)
{
    const int c   = blockIdx.x;     // 0..512 (512 = zero row)
    const int tid = threadIdx.x;

    if (c == VOC) {
        if (tid < NCOL) {
            int seg, local; col_map(tid, seg, local);
            pe[SEGBASE_H[seg] + VOC * SEGW_H[seg] + local] = __float2half(0.f);
        }
        return;
    }

    __shared__ float e[EMB];
    if (tid < EMB) e[tid] = emb[c * EMB + tid];
    __syncthreads();
    if (tid >= NCOL) return;

    float s = 0.f;
    #pragma unroll 8
    for (int i = 0; i < EMB; ++i) s += e[i] * wt[i * NCOL + tid];

    int seg, local; col_map(tid, seg, local);
    pe[SEGBASE_H[seg] + c * SEGW_H[seg] + local] = __float2half(s);
}

// -------- Kernel C: LDS-resident subtable conv + max --------
__device__ __forceinline__ float2 h2tof2(int u) {
    return __half22float2(__builtin_bit_cast(__half2, u));
}

template<int K> struct LdT;
template<> struct LdT<2> { using T = int;  };
template<> struct LdT<3> { using T = int2; };
template<> struct LdT<4> { using T = int2; };
template<> struct LdT<5> { using T = int4; };
template<> struct LdT<6> { using T = int4; };

template<int K>
__device__ __forceinline__ void unpack(typename LdT<K>::T q, float* v) {
    if constexpr (K == 2) {
        float2 f = h2tof2(q); v[0] = f.x; v[1] = f.y;
    } else if constexpr (K == 3) {
        float2 f0 = h2tof2(q.x), f1 = h2tof2(q.y);
        v[0] = f0.x; v[1] = f0.y; v[2] = f1.x;
    } else if constexpr (K == 4) {
        float2 f0 = h2tof2(q.x), f1 = h2tof2(q.y);
        v[0] = f0.x; v[1] = f0.y; v[2] = f1.x; v[3] = f1.y;
    } else if constexpr (K == 5) {
        float2 f0 = h2tof2(q.x), f1 = h2tof2(q.y), f2 = h2tof2(q.z);
        v[0] = f0.x; v[1] = f0.y; v[2] = f1.x; v[3] = f1.y; v[4] = f2.x;
    } else {
        float2 f0 = h2tof2(q.x), f1 = h2tof2(q.y), f2 = h2tof2(q.z);
        v[0] = f0.x; v[1] = f0.y; v[2] = f1.x; v[3] = f1.y;
        v[4] = f2.x; v[5] = f2.y;
    }
}

// tab: LDS subtable (rows of SEGW bytes, bank-aligned). sc: byte offsets.
template<int K, int PAD, int LANEB>
__device__ __forceinline__ float convseg(const char* __restrict__ tab,
                                         const int* __restrict__ sc,
                                         int w, int ol, float bias)
{
    using LT = typename LdT<K>::T;
    constexpr int LOUT = L_SEQ + 2 * PAD - K + 1;
    const int lb = ol * LANEB;

    float s[LOUT];
    #pragma unroll
    for (int t = 0; t < LOUT; ++t) s[t] = bias;

    #pragma unroll
    for (int g = 0; g < 4; ++g) {
        int off[8];
        #pragma unroll
        for (int u = 0; u < 8; ++u)
            off[u] = sc[(g * 8 + u) * SCPITCH + w] + lb;
        LT q[8];
        #pragma unroll
        for (int u = 0; u < 8; ++u)
            q[u] = *(const LT*)(tab + off[u]);
        #pragma unroll
        for (int u = 0; u < 8; ++u) {
            const int tp = g * 8 + u;
            float v[K];
            unpack<K>(q[u], v);
            #pragma unroll
            for (int j = 0; j < K; ++j) {
                int t = tp + PAD - j;
                if (t >= 0 && t < LOUT) s[t] += v[j];
            }
        }
    }

    float m = s[0];
    #pragma unroll
    for (int t = 1; t < LOUT; ++t) m = fmaxf(m, s[t]);
    return m;
}

__global__ __launch_bounds__(1024) void conv_max(
    const int*    __restrict__ word,
    const __half* __restrict__ pe,
    const float* __restrict__ b2, const float* __restrict__ b3,
    const float* __restrict__ b4, const float* __restrict__ b5,
    const float* __restrict__ b6,
    float*       __restrict__ out)
{
    // 131,328 B table + 16,512 B sc = 147,840 B (gfx950 LDS is 160 KiB/WG)
    __shared__ __align__(16) __half tab[65664];
    __shared__ int sc[L_SEQ * SCPITCH];

    const int tid   = threadIdx.x;
    const int seg   = blockIdx.x % 5;       // block-uniform
    const int wb    = blockIdx.x / 5;
    const int wbase = wb * WPB;

    const int segwH = SEGW_H[seg];
    const int nI4   = (513 * segwH) >> 3;   // int4 count (2052/4104/8208)

    // stage subtable: coalesced, L2-resident
    const int4* src = (const int4*)(pe + SEGBASE_H[seg]);
    int4* dst = (int4*)tab;
    for (int i = tid; i < nI4; i += 1024) dst[i] = src[i];

    // stage char byte-offsets, transposed with pitch 129 (conflict-free)
    const int segwB = segwH * 2;
    #pragma unroll
    for (int r = 0; r < 4; ++r) {
        int i = tid + r * 1024;             // 0..4095
        int c = word[wbase * L_SEQ + i];    // coalesced
        int w = i >> 5, tp = i & 31;
        sc[tp * SCPITCH + w] = (c >= 0 ? c : VOC) * segwB;
    }
    __syncthreads();

    const int ol = tid & 15;                // filter
    const int w0 = tid >> 4;                // word 0..63; second pair +64
    const float* bp;
    switch (seg) {
        case 0:  bp = b2; break; case 1: bp = b3; break;
        case 2:  bp = b4; break; case 3: bp = b5; break;
        default: bp = b6; break;
    }
    const float bias = bp[ol];
    const char* tb = (const char*)tab;

    float m0, m1;
    switch (seg) {
        case 0:  m0 = convseg<2, 0, 4 >(tb, sc, w0,      ol, bias);
                 m1 = convseg<2, 0, 4 >(tb, sc, w0 + 64, ol, bias); break;
        case 1:  m0 = convseg<3, 0, 8 >(tb, sc, w0,      ol, bias);
                 m1 = convseg<3, 0, 8 >(tb, sc, w0 + 64, ol, bias); break;
        case 2:  m0 = convseg<4, 1, 8 >(tb, sc, w0,      ol, bias);
                 m1 = convseg<4, 1, 8 >(tb, sc, w0 + 64, ol, bias); break;
        case 3:  m0 = convseg<5, 2, 16>(tb, sc, w0,      ol, bias);
                 m1 = convseg<5, 2, 16>(tb, sc, w0 + 64, ol, bias); break;
        default: m0 = convseg<6, 3, 16>(tb, sc, w0,      ol, bias);
                 m1 = convseg<6, 3, 16>(tb, sc, w0 + 64, ol, bias); break;
    }
    out[(wbase + w0     ) * 80 + seg * 16 + ol] = m0;
    out[(wbase + w0 + 64) * 80 + seg * 16 + ol] = m1;
}

extern "C" void kernel_launch(void* const* d_in, const int* in_sizes, int n_in,
                              void* d_out, int out_size, void* d_ws, size_t ws_size,
                              hipStream_t stream)
{
    const int*   word = (const int*)  d_in[0];
    const float* emb  = (const float*)d_in[1];
    const float* w2   = (const float*)d_in[2];
    const float* b2   = (const float*)d_in[3];
    const float* w3   = (const float*)d_in[4];
    const float* b3   = (const float*)d_in[5];
    const float* w4   = (const float*)d_in[6];
    const float* b4   = (const float*)d_in[7];
    const float* w5   = (const float*)d_in[8];
    const float* b5   = (const float*)d_in[9];
    const float* w6   = (const float*)d_in[10];
    const float* b6   = (const float*)d_in[11];
    float* out = (float*)d_out;

    // ws: pe16 seg-major [426,816 B], Wt fp32 at +430,080 [212,992 B]
    __half* pe16 = (__half*)d_ws;
    float*  wt   = (float*)((char*)d_ws + 430080);

    pack_wt<<<EMB, NCOL, 0, stream>>>(w2, w3, w4, w5, w6, wt);

    build_pe16<<<VOC + 1, 512, 0, stream>>>(emb, wt, pe16);

    conv_max<<<5 * (NWORDS / WPB), 1024, 0, stream>>>(
        word, pe16, b2, b3, b4, b5, b6, out);
}